// Round 1
// baseline (3039.069 us; speedup 1.0000x reference)
//
#include <hip/hip_runtime.h>
#include <math.h>

#define NODES  50000
#define EDGES  800000
#define GRAPHS 256
#define FEAT   128
#define STATE  64
#define M_OUT  32
#define ROUNDS 4

// ---------------------------------------------------------------------------
// Fused: state = relu(x @ inW + inb); message = relu(state @ msgW + msgb)
// 16 nodes per block-iteration, 256 threads: thread t -> node (t>>4), feats [(t&15)*4 .. +3]
// ---------------------------------------------------------------------------
__global__ __launch_bounds__(256) void k_in_msg(
    const float* __restrict__ x, const float* __restrict__ inW, const float* __restrict__ inb,
    const float* __restrict__ msgW, const float* __restrict__ msgb,
    float* __restrict__ state, float* __restrict__ message)
{
    __shared__ float sInW[FEAT * STATE];    // 32 KB
    __shared__ float sMsgW[STATE * STATE];  // 16 KB
    __shared__ float sInb[STATE], sMsgb[STATE];
    __shared__ float sx[16 * 132];          // x tile, stride 132 kills 4-way conflicts
    __shared__ float ss[16 * 68];           // new-state tile, stride 68

    for (int i = threadIdx.x; i < (FEAT * STATE) / 4; i += 256)
        *(float4*)(sInW + i * 4) = *(const float4*)(inW + i * 4);
    for (int i = threadIdx.x; i < (STATE * STATE) / 4; i += 256)
        *(float4*)(sMsgW + i * 4) = *(const float4*)(msgW + i * 4);
    if (threadIdx.x < STATE) {
        sInb[threadIdx.x]  = inb[threadIdx.x];
        sMsgb[threadIdx.x] = msgb[threadIdx.x];
    }

    const int ns = threadIdx.x >> 4;        // node within tile
    const int jg = (threadIdx.x & 15) << 2; // feature group

    for (int base = blockIdx.x * 16; base < NODES; base += gridDim.x * 16) {
        __syncthreads(); // protects sx/ss reuse (and first-iter weight loads)
        // stage 16 x-rows (2048 floats) via float4
        for (int i = threadIdx.x; i < 512; i += 256) {
            int row = i >> 5, q = (i & 31) << 2;
            int n = base + row;
            float4 v = make_float4(0.f, 0.f, 0.f, 0.f);
            if (n < NODES) v = *(const float4*)(x + (long)n * FEAT + q);
            *(float4*)(sx + row * 132 + q) = v;
        }
        __syncthreads();

        const int n = base + ns;
        float a0 = sInb[jg], a1 = sInb[jg + 1], a2 = sInb[jg + 2], a3 = sInb[jg + 3];
        const float* xr = sx + ns * 132;
        #pragma unroll 8
        for (int k = 0; k < FEAT; k++) {
            float xv = xr[k];
            float4 w = *(const float4*)(sInW + k * STATE + jg);
            a0 += xv * w.x; a1 += xv * w.y; a2 += xv * w.z; a3 += xv * w.w;
        }
        a0 = fmaxf(a0, 0.f); a1 = fmaxf(a1, 0.f); a2 = fmaxf(a2, 0.f); a3 = fmaxf(a3, 0.f);
        if (n < NODES) *(float4*)(state + (long)n * STATE + jg) = make_float4(a0, a1, a2, a3);
        *(float4*)(ss + ns * 68 + jg) = make_float4(a0, a1, a2, a3);
        __syncthreads();

        float m0 = sMsgb[jg], m1 = sMsgb[jg + 1], m2 = sMsgb[jg + 2], m3 = sMsgb[jg + 3];
        const float* sr = ss + ns * 68;
        #pragma unroll 8
        for (int k = 0; k < STATE; k++) {
            float sv = sr[k];
            float4 w = *(const float4*)(sMsgW + k * STATE + jg);
            m0 += sv * w.x; m1 += sv * w.y; m2 += sv * w.z; m3 += sv * w.w;
        }
        m0 = fmaxf(m0, 0.f); m1 = fmaxf(m1, 0.f); m2 = fmaxf(m2, 0.f); m3 = fmaxf(m3, 0.f);
        if (n < NODES) *(float4*)(message + (long)n * STATE + jg) = make_float4(m0, m1, m2, m3);
    }
}

// ---------------------------------------------------------------------------
// Scatter-add: agg[dst] += message[src] over all edges. 256 edges/block,
// indices staged in LDS, float4 gather, 4 scalar atomics per thread.
// ---------------------------------------------------------------------------
__global__ __launch_bounds__(256) void k_scatter(
    const float* __restrict__ msg, const int* __restrict__ ei, float* __restrict__ agg)
{
    __shared__ int se[256], sd[256];
    const int e0 = blockIdx.x * 256;
    if (e0 + (int)threadIdx.x < EDGES) {
        se[threadIdx.x] = ei[e0 + threadIdx.x];
        sd[threadIdx.x] = ei[EDGES + e0 + threadIdx.x];
    }
    __syncthreads();
    const int f = (threadIdx.x & 15) << 2;
    #pragma unroll
    for (int i = 0; i < 16; i++) {
        int le = (threadIdx.x >> 4) + i * 16;
        int e = e0 + le;
        if (e < EDGES) {
            float4 v = *(const float4*)(msg + (long)se[le] * STATE + f);
            float* a = agg + (long)sd[le] * STATE + f;
            atomicAdd(a + 0, v.x);
            atomicAdd(a + 1, v.y);
            atomicAdd(a + 2, v.z);
            atomicAdd(a + 3, v.w);
        }
    }
}

// ---------------------------------------------------------------------------
// Fused: state += relu(agg @ updW + updb); message = relu(state @ msgW + msgb)
// Also re-zeroes agg in place for the next round.
// ---------------------------------------------------------------------------
__global__ __launch_bounds__(256) void k_upd_msg(
    const float* __restrict__ updW, const float* __restrict__ updb,
    const float* __restrict__ msgW, const float* __restrict__ msgb,
    float* __restrict__ agg, float* __restrict__ state, float* __restrict__ message)
{
    __shared__ float sUpdW[STATE * STATE], sMsgW[STATE * STATE]; // 16 KB each
    __shared__ float sUpdb[STATE], sMsgb[STATE];
    __shared__ float sa[16 * 68], ss[16 * 68];

    for (int i = threadIdx.x; i < (STATE * STATE) / 4; i += 256) {
        *(float4*)(sUpdW + i * 4) = *(const float4*)(updW + i * 4);
        *(float4*)(sMsgW + i * 4) = *(const float4*)(msgW + i * 4);
    }
    if (threadIdx.x < STATE) {
        sUpdb[threadIdx.x] = updb[threadIdx.x];
        sMsgb[threadIdx.x] = msgb[threadIdx.x];
    }

    const int ns = threadIdx.x >> 4;
    const int jg = (threadIdx.x & 15) << 2;

    for (int base = blockIdx.x * 16; base < NODES; base += gridDim.x * 16) {
        __syncthreads();
        // stage 16 agg rows (1024 floats) and zero them in global
        for (int i = threadIdx.x; i < 256; i += 256) {
            int row = i >> 4, q = (i & 15) << 2;
            int n = base + row;
            float4 v = make_float4(0.f, 0.f, 0.f, 0.f);
            if (n < NODES) {
                v = *(const float4*)(agg + (long)n * STATE + q);
                *(float4*)(agg + (long)n * STATE + q) = make_float4(0.f, 0.f, 0.f, 0.f);
            }
            *(float4*)(sa + row * 68 + q) = v;
        }
        __syncthreads();

        const int n = base + ns;
        float a0 = sUpdb[jg], a1 = sUpdb[jg + 1], a2 = sUpdb[jg + 2], a3 = sUpdb[jg + 3];
        const float* ar = sa + ns * 68;
        #pragma unroll 8
        for (int k = 0; k < STATE; k++) {
            float av = ar[k];
            float4 w = *(const float4*)(sUpdW + k * STATE + jg);
            a0 += av * w.x; a1 += av * w.y; a2 += av * w.z; a3 += av * w.w;
        }
        a0 = fmaxf(a0, 0.f); a1 = fmaxf(a1, 0.f); a2 = fmaxf(a2, 0.f); a3 = fmaxf(a3, 0.f);
        float4 st = make_float4(0.f, 0.f, 0.f, 0.f);
        if (n < NODES) st = *(const float4*)(state + (long)n * STATE + jg);
        float s0 = st.x + a0, s1 = st.y + a1, s2 = st.z + a2, s3 = st.w + a3;
        if (n < NODES) *(float4*)(state + (long)n * STATE + jg) = make_float4(s0, s1, s2, s3);
        *(float4*)(ss + ns * 68 + jg) = make_float4(s0, s1, s2, s3);
        __syncthreads();

        float m0 = sMsgb[jg], m1 = sMsgb[jg + 1], m2 = sMsgb[jg + 2], m3 = sMsgb[jg + 3];
        const float* sr = ss + ns * 68;
        #pragma unroll 8
        for (int k = 0; k < STATE; k++) {
            float sv = sr[k];
            float4 w = *(const float4*)(sMsgW + k * STATE + jg);
            m0 += sv * w.x; m1 += sv * w.y; m2 += sv * w.z; m3 += sv * w.w;
        }
        m0 = fmaxf(m0, 0.f); m1 = fmaxf(m1, 0.f); m2 = fmaxf(m2, 0.f); m3 = fmaxf(m3, 0.f);
        if (n < NODES) *(float4*)(message + (long)n * STATE + jg) = make_float4(m0, m1, m2, m3);
    }
}

// ---------------------------------------------------------------------------
// Last round fused with graph pooling: s = state + relu(agg@updW+b);
// graph_state[batch[n]] += s  (atomic). state itself is dead afterwards.
// ---------------------------------------------------------------------------
__global__ __launch_bounds__(256) void k_upd_pool(
    const float* __restrict__ updW, const float* __restrict__ updb,
    const float* __restrict__ agg, const float* __restrict__ state,
    const int* __restrict__ batch, float* __restrict__ gs)
{
    __shared__ float sUpdW[STATE * STATE];
    __shared__ float sUpdb[STATE];
    __shared__ float sa[16 * 68];

    for (int i = threadIdx.x; i < (STATE * STATE) / 4; i += 256)
        *(float4*)(sUpdW + i * 4) = *(const float4*)(updW + i * 4);
    if (threadIdx.x < STATE) sUpdb[threadIdx.x] = updb[threadIdx.x];

    const int ns = threadIdx.x >> 4;
    const int jg = (threadIdx.x & 15) << 2;

    for (int base = blockIdx.x * 16; base < NODES; base += gridDim.x * 16) {
        __syncthreads();
        for (int i = threadIdx.x; i < 256; i += 256) {
            int row = i >> 4, q = (i & 15) << 2;
            int n = base + row;
            float4 v = make_float4(0.f, 0.f, 0.f, 0.f);
            if (n < NODES) v = *(const float4*)(agg + (long)n * STATE + q);
            *(float4*)(sa + row * 68 + q) = v;
        }
        __syncthreads();

        const int n = base + ns;
        float a0 = sUpdb[jg], a1 = sUpdb[jg + 1], a2 = sUpdb[jg + 2], a3 = sUpdb[jg + 3];
        const float* ar = sa + ns * 68;
        #pragma unroll 8
        for (int k = 0; k < STATE; k++) {
            float av = ar[k];
            float4 w = *(const float4*)(sUpdW + k * STATE + jg);
            a0 += av * w.x; a1 += av * w.y; a2 += av * w.z; a3 += av * w.w;
        }
        a0 = fmaxf(a0, 0.f); a1 = fmaxf(a1, 0.f); a2 = fmaxf(a2, 0.f); a3 = fmaxf(a3, 0.f);
        if (n < NODES) {
            float4 st = *(const float4*)(state + (long)n * STATE + jg);
            int g = batch[n];
            float* p = gs + (long)g * STATE + jg;
            atomicAdd(p + 0, st.x + a0);
            atomicAdd(p + 1, st.y + a1);
            atomicAdd(p + 2, st.z + a2);
            atomicAdd(p + 3, st.w + a3);
        }
    }
}

// ---------------------------------------------------------------------------
// mean = gs@meanW+b ; std = exp(0.5*clip(gs@lvW+b, -20, 2)) -> out[2,256,32]
// ---------------------------------------------------------------------------
__global__ __launch_bounds__(64) void k_final(
    const float* __restrict__ gs,
    const float* __restrict__ meanW, const float* __restrict__ meanb,
    const float* __restrict__ lvW, const float* __restrict__ lvb,
    float* __restrict__ out)
{
    __shared__ float row[STATE];
    const int g = blockIdx.x;
    const int j = threadIdx.x;
    row[j] = gs[g * STATE + j];
    __syncthreads();
    if (j < M_OUT) {
        float acc = meanb[j];
        #pragma unroll
        for (int k = 0; k < STATE; k++) acc += row[k] * meanW[k * M_OUT + j];
        out[g * M_OUT + j] = acc;
    } else {
        int jj = j - M_OUT;
        float acc = lvb[jj];
        #pragma unroll
        for (int k = 0; k < STATE; k++) acc += row[k] * lvW[k * M_OUT + jj];
        acc = fminf(fmaxf(acc, -20.f), 2.f);
        out[GRAPHS * M_OUT + g * M_OUT + jj] = expf(0.5f * acc);
    }
}

extern "C" void kernel_launch(void* const* d_in, const int* in_sizes, int n_in,
                              void* d_out, int out_size, void* d_ws, size_t ws_size,
                              hipStream_t stream) {
    const float* x     = (const float*)d_in[0];
    const int*   ei    = (const int*)d_in[1];   // [2, E]: row0 = src (gather), row1 = dst (scatter)
    const int*   batch = (const int*)d_in[2];
    const float* inW   = (const float*)d_in[3];
    const float* inb   = (const float*)d_in[4];
    const float* msgW  = (const float*)d_in[5]; // [4,64,64]
    const float* msgb  = (const float*)d_in[6]; // [4,64]
    const float* updW  = (const float*)d_in[7];
    const float* updb  = (const float*)d_in[8];
    const float* meanW = (const float*)d_in[9];
    const float* meanb = (const float*)d_in[10];
    const float* lvW   = (const float*)d_in[11];
    const float* lvb   = (const float*)d_in[12];
    float* out = (float*)d_out;

    const size_t NS = (size_t)NODES * STATE * sizeof(float); // 12.8 MB, 256B-aligned
    char* ws = (char*)d_ws;
    float* state   = (float*)(ws);
    float* message = (float*)(ws + NS);
    float* agg     = (float*)(ws + 2 * NS);
    float* gs      = (float*)(ws + 3 * NS);

    hipMemsetAsync(agg, 0, NS, stream);
    hipMemsetAsync(gs, 0, (size_t)GRAPHS * STATE * sizeof(float), stream);

    k_in_msg<<<1024, 256, 0, stream>>>(x, inW, inb, msgW, msgb, state, message);
    for (int r = 0; r < ROUNDS; r++) {
        k_scatter<<<(EDGES + 255) / 256, 256, 0, stream>>>(message, ei, agg);
        if (r < ROUNDS - 1) {
            k_upd_msg<<<1024, 256, 0, stream>>>(updW + r * STATE * STATE, updb + r * STATE,
                                                msgW + (r + 1) * STATE * STATE, msgb + (r + 1) * STATE,
                                                agg, state, message);
        } else {
            k_upd_pool<<<1024, 256, 0, stream>>>(updW + r * STATE * STATE, updb + r * STATE,
                                                 agg, state, batch, gs);
        }
    }
    k_final<<<GRAPHS, 64, 0, stream>>>(gs, meanW, meanb, lvW, lvb, out);
}

// Round 2
// 632.047 us; speedup vs baseline: 4.8083x; 4.8083x over previous
//
#include <hip/hip_runtime.h>
#include <math.h>

#define NODES  50000
#define EDGES  800000
#define GRAPHS 256
#define FEAT   128
#define STATE  64
#define M_OUT  32
#define ROUNDS 4

// ---------------------------------------------------------------------------
// Fused: state = relu(x @ inW + inb); message = relu(state @ msgW + msgb)
// 16 nodes per block-iteration, 256 threads: thread t -> node (t>>4), feats [(t&15)*4 .. +3]
// ---------------------------------------------------------------------------
__global__ __launch_bounds__(256) void k_in_msg(
    const float* __restrict__ x, const float* __restrict__ inW, const float* __restrict__ inb,
    const float* __restrict__ msgW, const float* __restrict__ msgb,
    float* __restrict__ state, float* __restrict__ message)
{
    __shared__ float sInW[FEAT * STATE];    // 32 KB
    __shared__ float sMsgW[STATE * STATE];  // 16 KB
    __shared__ float sInb[STATE], sMsgb[STATE];
    __shared__ float sx[16 * 132];          // x tile, stride 132 kills 4-way conflicts
    __shared__ float ss[16 * 68];           // new-state tile, stride 68

    for (int i = threadIdx.x; i < (FEAT * STATE) / 4; i += 256)
        *(float4*)(sInW + i * 4) = *(const float4*)(inW + i * 4);
    for (int i = threadIdx.x; i < (STATE * STATE) / 4; i += 256)
        *(float4*)(sMsgW + i * 4) = *(const float4*)(msgW + i * 4);
    if (threadIdx.x < STATE) {
        sInb[threadIdx.x]  = inb[threadIdx.x];
        sMsgb[threadIdx.x] = msgb[threadIdx.x];
    }

    const int ns = threadIdx.x >> 4;        // node within tile
    const int jg = (threadIdx.x & 15) << 2; // feature group

    for (int base = blockIdx.x * 16; base < NODES; base += gridDim.x * 16) {
        __syncthreads(); // protects sx/ss reuse (and first-iter weight loads)
        for (int i = threadIdx.x; i < 512; i += 256) {
            int row = i >> 5, q = (i & 31) << 2;
            int n = base + row;
            float4 v = make_float4(0.f, 0.f, 0.f, 0.f);
            if (n < NODES) v = *(const float4*)(x + (long)n * FEAT + q);
            *(float4*)(sx + row * 132 + q) = v;
        }
        __syncthreads();

        const int n = base + ns;
        float a0 = sInb[jg], a1 = sInb[jg + 1], a2 = sInb[jg + 2], a3 = sInb[jg + 3];
        const float* xr = sx + ns * 132;
        #pragma unroll 8
        for (int k = 0; k < FEAT; k++) {
            float xv = xr[k];
            float4 w = *(const float4*)(sInW + k * STATE + jg);
            a0 += xv * w.x; a1 += xv * w.y; a2 += xv * w.z; a3 += xv * w.w;
        }
        a0 = fmaxf(a0, 0.f); a1 = fmaxf(a1, 0.f); a2 = fmaxf(a2, 0.f); a3 = fmaxf(a3, 0.f);
        if (n < NODES) *(float4*)(state + (long)n * STATE + jg) = make_float4(a0, a1, a2, a3);
        *(float4*)(ss + ns * 68 + jg) = make_float4(a0, a1, a2, a3);
        __syncthreads();

        float m0 = sMsgb[jg], m1 = sMsgb[jg + 1], m2 = sMsgb[jg + 2], m3 = sMsgb[jg + 3];
        const float* sr = ss + ns * 68;
        #pragma unroll 8
        for (int k = 0; k < STATE; k++) {
            float sv = sr[k];
            float4 w = *(const float4*)(sMsgW + k * STATE + jg);
            m0 += sv * w.x; m1 += sv * w.y; m2 += sv * w.z; m3 += sv * w.w;
        }
        m0 = fmaxf(m0, 0.f); m1 = fmaxf(m1, 0.f); m2 = fmaxf(m2, 0.f); m3 = fmaxf(m3, 0.f);
        if (n < NODES) *(float4*)(message + (long)n * STATE + jg) = make_float4(m0, m1, m2, m3);
    }
}

// ---------------------------------------------------------------------------
// CSR build step 1: degree histogram over dst
// ---------------------------------------------------------------------------
__global__ __launch_bounds__(256) void k_hist(const int* __restrict__ ei, int* __restrict__ deg)
{
    int e = blockIdx.x * 256 + threadIdx.x;
    if (e < EDGES) atomicAdd(&deg[ei[EDGES + e]], 1);
}

// ---------------------------------------------------------------------------
// CSR build step 2: exclusive scan of deg -> rowptr, cursor (single block,
// 1024 threads = 16 waves; wave shuffle scan + 16-entry LDS scan)
// ---------------------------------------------------------------------------
__global__ __launch_bounds__(1024) void k_scan(const int* __restrict__ deg,
                                               int* __restrict__ rowptr,
                                               int* __restrict__ cursor)
{
    __shared__ int wsum[16];
    __shared__ int carry;
    const int tid = threadIdx.x;
    const int lane = tid & 63, wid = tid >> 6;
    if (tid == 0) carry = 0;
    __syncthreads();
    for (int base = 0; base < NODES; base += 1024) {
        int v = (base + tid < NODES) ? deg[base + tid] : 0;
        int incl = v;
        #pragma unroll
        for (int off = 1; off < 64; off <<= 1) {
            int t = __shfl_up(incl, off, 64);
            if (lane >= off) incl += t;
        }
        if (lane == 63) wsum[wid] = incl;
        __syncthreads();
        if (tid < 16) {
            int t = wsum[tid];
            #pragma unroll
            for (int off = 1; off < 16; off <<= 1) {
                int u = __shfl_up(t, off, 64);
                if (tid >= off) t += u;
            }
            wsum[tid] = t;
        }
        __syncthreads();
        int wbase = (wid == 0) ? 0 : wsum[wid - 1];
        int excl = carry + wbase + incl - v;
        if (base + tid < NODES) { rowptr[base + tid] = excl; cursor[base + tid] = excl; }
        int tot = wsum[15];
        __syncthreads();
        if (tid == 0) carry += tot;
        __syncthreads();
    }
    if (tid == 0) rowptr[NODES] = carry;
}

// ---------------------------------------------------------------------------
// CSR build step 3: fill csr_src with the src of each edge, bucketed by dst
// ---------------------------------------------------------------------------
__global__ __launch_bounds__(256) void k_fill(const int* __restrict__ ei,
                                              int* __restrict__ cursor,
                                              int* __restrict__ csr)
{
    int e = blockIdx.x * 256 + threadIdx.x;
    if (e < EDGES) {
        int src = ei[e];
        int dst = ei[EDGES + e];
        int slot = atomicAdd(&cursor[dst], 1);
        csr[slot] = src;
    }
}

// ---------------------------------------------------------------------------
// Pull-mode aggregation fused with update + next message:
//   agg[n] = sum_{e: dst=n} message[src(e)]
//   state[n] += relu(agg @ updW + updb)
//   msg_out[n] = relu(state @ msgW + msgb)
// ---------------------------------------------------------------------------
__global__ __launch_bounds__(256) void k_agg_upd_msg(
    const float* __restrict__ updW, const float* __restrict__ updb,
    const float* __restrict__ msgW, const float* __restrict__ msgb,
    const int* __restrict__ rowptr, const int* __restrict__ csr,
    const float* __restrict__ msg_in,
    float* __restrict__ state, float* __restrict__ msg_out)
{
    __shared__ float sUpdW[STATE * STATE], sMsgW[STATE * STATE];
    __shared__ float sUpdb[STATE], sMsgb[STATE];
    __shared__ float sa[16 * 68], ss[16 * 68];

    for (int i = threadIdx.x; i < (STATE * STATE) / 4; i += 256) {
        *(float4*)(sUpdW + i * 4) = *(const float4*)(updW + i * 4);
        *(float4*)(sMsgW + i * 4) = *(const float4*)(msgW + i * 4);
    }
    if (threadIdx.x < STATE) {
        sUpdb[threadIdx.x] = updb[threadIdx.x];
        sMsgb[threadIdx.x] = msgb[threadIdx.x];
    }

    const int ns = threadIdx.x >> 4;
    const int jg = (threadIdx.x & 15) << 2;

    for (int base = blockIdx.x * 16; base < NODES; base += gridDim.x * 16) {
        const int n = base + ns;
        // gather-sum incoming messages (2-way unrolled for MLP latency overlap)
        float4 acc = make_float4(0.f, 0.f, 0.f, 0.f);
        if (n < NODES) {
            int beg = rowptr[n], end = rowptr[n + 1];
            int i = beg;
            for (; i + 1 < end; i += 2) {
                int s0 = csr[i], s1 = csr[i + 1];
                float4 v0 = *(const float4*)(msg_in + (long)s0 * STATE + jg);
                float4 v1 = *(const float4*)(msg_in + (long)s1 * STATE + jg);
                acc.x += v0.x + v1.x; acc.y += v0.y + v1.y;
                acc.z += v0.z + v1.z; acc.w += v0.w + v1.w;
            }
            if (i < end) {
                int s0 = csr[i];
                float4 v0 = *(const float4*)(msg_in + (long)s0 * STATE + jg);
                acc.x += v0.x; acc.y += v0.y; acc.z += v0.z; acc.w += v0.w;
            }
        }
        __syncthreads(); // prev-iter readers of sa/ss done (and first-iter weight staging)
        *(float4*)(sa + ns * 68 + jg) = acc;
        __syncthreads();

        float a0 = sUpdb[jg], a1 = sUpdb[jg + 1], a2 = sUpdb[jg + 2], a3 = sUpdb[jg + 3];
        const float* ar = sa + ns * 68;
        #pragma unroll 8
        for (int k = 0; k < STATE; k++) {
            float av = ar[k];
            float4 w = *(const float4*)(sUpdW + k * STATE + jg);
            a0 += av * w.x; a1 += av * w.y; a2 += av * w.z; a3 += av * w.w;
        }
        a0 = fmaxf(a0, 0.f); a1 = fmaxf(a1, 0.f); a2 = fmaxf(a2, 0.f); a3 = fmaxf(a3, 0.f);
        float4 st = make_float4(0.f, 0.f, 0.f, 0.f);
        if (n < NODES) st = *(const float4*)(state + (long)n * STATE + jg);
        float s0 = st.x + a0, s1 = st.y + a1, s2 = st.z + a2, s3 = st.w + a3;
        if (n < NODES) *(float4*)(state + (long)n * STATE + jg) = make_float4(s0, s1, s2, s3);
        *(float4*)(ss + ns * 68 + jg) = make_float4(s0, s1, s2, s3);
        __syncthreads();

        float m0 = sMsgb[jg], m1 = sMsgb[jg + 1], m2 = sMsgb[jg + 2], m3 = sMsgb[jg + 3];
        const float* sr = ss + ns * 68;
        #pragma unroll 8
        for (int k = 0; k < STATE; k++) {
            float sv = sr[k];
            float4 w = *(const float4*)(sMsgW + k * STATE + jg);
            m0 += sv * w.x; m1 += sv * w.y; m2 += sv * w.z; m3 += sv * w.w;
        }
        m0 = fmaxf(m0, 0.f); m1 = fmaxf(m1, 0.f); m2 = fmaxf(m2, 0.f); m3 = fmaxf(m3, 0.f);
        if (n < NODES) *(float4*)(msg_out + (long)n * STATE + jg) = make_float4(m0, m1, m2, m3);
    }
}

// ---------------------------------------------------------------------------
// Last round: aggregation + update fused with graph pooling.
// ---------------------------------------------------------------------------
__global__ __launch_bounds__(256) void k_agg_upd_pool(
    const float* __restrict__ updW, const float* __restrict__ updb,
    const int* __restrict__ rowptr, const int* __restrict__ csr,
    const float* __restrict__ msg_in,
    const float* __restrict__ state, const int* __restrict__ batch,
    float* __restrict__ gs)
{
    __shared__ float sUpdW[STATE * STATE];
    __shared__ float sUpdb[STATE];
    __shared__ float sa[16 * 68];

    for (int i = threadIdx.x; i < (STATE * STATE) / 4; i += 256)
        *(float4*)(sUpdW + i * 4) = *(const float4*)(updW + i * 4);
    if (threadIdx.x < STATE) sUpdb[threadIdx.x] = updb[threadIdx.x];

    const int ns = threadIdx.x >> 4;
    const int jg = (threadIdx.x & 15) << 2;

    for (int base = blockIdx.x * 16; base < NODES; base += gridDim.x * 16) {
        const int n = base + ns;
        float4 acc = make_float4(0.f, 0.f, 0.f, 0.f);
        if (n < NODES) {
            int beg = rowptr[n], end = rowptr[n + 1];
            int i = beg;
            for (; i + 1 < end; i += 2) {
                int s0 = csr[i], s1 = csr[i + 1];
                float4 v0 = *(const float4*)(msg_in + (long)s0 * STATE + jg);
                float4 v1 = *(const float4*)(msg_in + (long)s1 * STATE + jg);
                acc.x += v0.x + v1.x; acc.y += v0.y + v1.y;
                acc.z += v0.z + v1.z; acc.w += v0.w + v1.w;
            }
            if (i < end) {
                int s0 = csr[i];
                float4 v0 = *(const float4*)(msg_in + (long)s0 * STATE + jg);
                acc.x += v0.x; acc.y += v0.y; acc.z += v0.z; acc.w += v0.w;
            }
        }
        __syncthreads();
        *(float4*)(sa + ns * 68 + jg) = acc;
        __syncthreads();

        float a0 = sUpdb[jg], a1 = sUpdb[jg + 1], a2 = sUpdb[jg + 2], a3 = sUpdb[jg + 3];
        const float* ar = sa + ns * 68;
        #pragma unroll 8
        for (int k = 0; k < STATE; k++) {
            float av = ar[k];
            float4 w = *(const float4*)(sUpdW + k * STATE + jg);
            a0 += av * w.x; a1 += av * w.y; a2 += av * w.z; a3 += av * w.w;
        }
        a0 = fmaxf(a0, 0.f); a1 = fmaxf(a1, 0.f); a2 = fmaxf(a2, 0.f); a3 = fmaxf(a3, 0.f);
        if (n < NODES) {
            float4 st = *(const float4*)(state + (long)n * STATE + jg);
            int g = batch[n];
            float* p = gs + (long)g * STATE + jg;
            atomicAdd(p + 0, st.x + a0);
            atomicAdd(p + 1, st.y + a1);
            atomicAdd(p + 2, st.z + a2);
            atomicAdd(p + 3, st.w + a3);
        }
    }
}

// ---------------------------------------------------------------------------
// mean = gs@meanW+b ; std = exp(0.5*clip(gs@lvW+b, -20, 2)) -> out[2,256,32]
// ---------------------------------------------------------------------------
__global__ __launch_bounds__(64) void k_final(
    const float* __restrict__ gs,
    const float* __restrict__ meanW, const float* __restrict__ meanb,
    const float* __restrict__ lvW, const float* __restrict__ lvb,
    float* __restrict__ out)
{
    __shared__ float row[STATE];
    const int g = blockIdx.x;
    const int j = threadIdx.x;
    row[j] = gs[g * STATE + j];
    __syncthreads();
    if (j < M_OUT) {
        float acc = meanb[j];
        #pragma unroll
        for (int k = 0; k < STATE; k++) acc += row[k] * meanW[k * M_OUT + j];
        out[g * M_OUT + j] = acc;
    } else {
        int jj = j - M_OUT;
        float acc = lvb[jj];
        #pragma unroll
        for (int k = 0; k < STATE; k++) acc += row[k] * lvW[k * M_OUT + jj];
        acc = fminf(fmaxf(acc, -20.f), 2.f);
        out[GRAPHS * M_OUT + g * M_OUT + jj] = expf(0.5f * acc);
    }
}

extern "C" void kernel_launch(void* const* d_in, const int* in_sizes, int n_in,
                              void* d_out, int out_size, void* d_ws, size_t ws_size,
                              hipStream_t stream) {
    const float* x     = (const float*)d_in[0];
    const int*   ei    = (const int*)d_in[1];   // [2, E]: row0 = src (gather), row1 = dst (scatter)
    const int*   batch = (const int*)d_in[2];
    const float* inW   = (const float*)d_in[3];
    const float* inb   = (const float*)d_in[4];
    const float* msgW  = (const float*)d_in[5]; // [4,64,64]
    const float* msgb  = (const float*)d_in[6]; // [4,64]
    const float* updW  = (const float*)d_in[7];
    const float* updb  = (const float*)d_in[8];
    const float* meanW = (const float*)d_in[9];
    const float* meanb = (const float*)d_in[10];
    const float* lvW   = (const float*)d_in[11];
    const float* lvb   = (const float*)d_in[12];
    float* out = (float*)d_out;

    const size_t NS = (size_t)NODES * STATE * sizeof(float); // 12.8 MB
    char* ws = (char*)d_ws;
    size_t off = 0;
    auto alloc = [&](size_t bytes) { void* p = ws + off; off += (bytes + 255) & ~(size_t)255; return p; };
    float* state   = (float*)alloc(NS);
    float* msgA    = (float*)alloc(NS);
    float* msgB    = (float*)alloc(NS);
    float* gs      = (float*)alloc((size_t)GRAPHS * STATE * sizeof(float));
    int*   deg     = (int*)alloc((size_t)NODES * sizeof(int));
    int*   rowptr  = (int*)alloc((size_t)(NODES + 1) * sizeof(int));
    int*   cursor  = (int*)alloc((size_t)NODES * sizeof(int));
    int*   csr     = (int*)alloc((size_t)EDGES * sizeof(int));

    hipMemsetAsync(deg, 0, (size_t)NODES * sizeof(int), stream);
    hipMemsetAsync(gs, 0, (size_t)GRAPHS * STATE * sizeof(float), stream);

    // CSR build (concurrent-safe ordering on one stream)
    k_hist<<<(EDGES + 255) / 256, 256, 0, stream>>>(ei, deg);
    k_scan<<<1, 1024, 0, stream>>>(deg, rowptr, cursor);
    k_fill<<<(EDGES + 255) / 256, 256, 0, stream>>>(ei, cursor, csr);

    k_in_msg<<<1024, 256, 0, stream>>>(x, inW, inb, msgW, msgb, state, msgA);

    float* mi = msgA; float* mo = msgB;
    for (int r = 0; r < ROUNDS - 1; r++) {
        k_agg_upd_msg<<<1024, 256, 0, stream>>>(
            updW + r * STATE * STATE, updb + r * STATE,
            msgW + (r + 1) * STATE * STATE, msgb + (r + 1) * STATE,
            rowptr, csr, mi, state, mo);
        float* t = mi; mi = mo; mo = t;
    }
    k_agg_upd_pool<<<1024, 256, 0, stream>>>(
        updW + (ROUNDS - 1) * STATE * STATE, updb + (ROUNDS - 1) * STATE,
        rowptr, csr, mi, state, batch, gs);

    k_final<<<GRAPHS, 64, 0, stream>>>(gs, meanW, meanb, lvW, lvb, out);
}

// Round 3
// 541.645 us; speedup vs baseline: 5.6108x; 1.1669x over previous
//
#include <hip/hip_runtime.h>
#include <math.h>

#define NODES  50000
#define EDGES  800000
#define GRAPHS 256
#define FEAT   128
#define STATE  64
#define M_OUT  32
#define ROUNDS 4
#define NTILES ((NODES + 15) / 16)

// ---------------------------------------------------------------------------
// 8-deep MLP gather: sum of msg[csr[beg..end)] float4-slices at offset jg.
// 8 independent csr loads then 8 independent gathers in flight; tail edges
// are clamped to end-1 and masked out with a 0 multiplier (keeps full MLP).
// ---------------------------------------------------------------------------
__device__ __forceinline__ float4 gather_sum8(const int* __restrict__ csr,
                                              const float* __restrict__ msg,
                                              int beg, int end, int jg)
{
    float4 acc = make_float4(0.f, 0.f, 0.f, 0.f);
    for (int i = beg; i < end; i += 8) {
        int last = end - 1;
        int i1 = i + 1 < last ? i + 1 : last;
        int i2 = i + 2 < last ? i + 2 : last;
        int i3 = i + 3 < last ? i + 3 : last;
        int i4 = i + 4 < last ? i + 4 : last;
        int i5 = i + 5 < last ? i + 5 : last;
        int i6 = i + 6 < last ? i + 6 : last;
        int i7 = i + 7 < last ? i + 7 : last;
        int s0 = csr[i],  s1 = csr[i1], s2 = csr[i2], s3 = csr[i3];
        int s4 = csr[i4], s5 = csr[i5], s6 = csr[i6], s7 = csr[i7];
        float4 v0 = *(const float4*)(msg + (long)s0 * STATE + jg);
        float4 v1 = *(const float4*)(msg + (long)s1 * STATE + jg);
        float4 v2 = *(const float4*)(msg + (long)s2 * STATE + jg);
        float4 v3 = *(const float4*)(msg + (long)s3 * STATE + jg);
        float4 v4 = *(const float4*)(msg + (long)s4 * STATE + jg);
        float4 v5 = *(const float4*)(msg + (long)s5 * STATE + jg);
        float4 v6 = *(const float4*)(msg + (long)s6 * STATE + jg);
        float4 v7 = *(const float4*)(msg + (long)s7 * STATE + jg);
        float m1 = (i + 1 < end) ? 1.f : 0.f;
        float m2 = (i + 2 < end) ? 1.f : 0.f;
        float m3 = (i + 3 < end) ? 1.f : 0.f;
        float m4 = (i + 4 < end) ? 1.f : 0.f;
        float m5 = (i + 5 < end) ? 1.f : 0.f;
        float m6 = (i + 6 < end) ? 1.f : 0.f;
        float m7 = (i + 7 < end) ? 1.f : 0.f;
        acc.x += v0.x; acc.y += v0.y; acc.z += v0.z; acc.w += v0.w;
        acc.x += v1.x * m1; acc.y += v1.y * m1; acc.z += v1.z * m1; acc.w += v1.w * m1;
        acc.x += v2.x * m2; acc.y += v2.y * m2; acc.z += v2.z * m2; acc.w += v2.w * m2;
        acc.x += v3.x * m3; acc.y += v3.y * m3; acc.z += v3.z * m3; acc.w += v3.w * m3;
        acc.x += v4.x * m4; acc.y += v4.y * m4; acc.z += v4.z * m4; acc.w += v4.w * m4;
        acc.x += v5.x * m5; acc.y += v5.y * m5; acc.z += v5.z * m5; acc.w += v5.w * m5;
        acc.x += v6.x * m6; acc.y += v6.y * m6; acc.z += v6.z * m6; acc.w += v6.w * m6;
        acc.x += v7.x * m7; acc.y += v7.y * m7; acc.z += v7.z * m7; acc.w += v7.w * m7;
    }
    return acc;
}

// ---------------------------------------------------------------------------
// Fused: state = relu(x @ inW + inb); message = relu(state @ msgW + msgb)
// ---------------------------------------------------------------------------
__global__ __launch_bounds__(256) void k_in_msg(
    const float* __restrict__ x, const float* __restrict__ inW, const float* __restrict__ inb,
    const float* __restrict__ msgW, const float* __restrict__ msgb,
    float* __restrict__ state, float* __restrict__ message)
{
    __shared__ float sInW[FEAT * STATE];    // 32 KB
    __shared__ float sMsgW[STATE * STATE];  // 16 KB
    __shared__ float sInb[STATE], sMsgb[STATE];
    __shared__ float sx[16 * 132];
    __shared__ float ss[16 * 68];

    for (int i = threadIdx.x; i < (FEAT * STATE) / 4; i += 256)
        *(float4*)(sInW + i * 4) = *(const float4*)(inW + i * 4);
    for (int i = threadIdx.x; i < (STATE * STATE) / 4; i += 256)
        *(float4*)(sMsgW + i * 4) = *(const float4*)(msgW + i * 4);
    if (threadIdx.x < STATE) {
        sInb[threadIdx.x]  = inb[threadIdx.x];
        sMsgb[threadIdx.x] = msgb[threadIdx.x];
    }

    const int ns = threadIdx.x >> 4;
    const int jg = (threadIdx.x & 15) << 2;

    for (int base = blockIdx.x * 16; base < NODES; base += gridDim.x * 16) {
        __syncthreads();
        for (int i = threadIdx.x; i < 512; i += 256) {
            int row = i >> 5, q = (i & 31) << 2;
            int n = base + row;
            float4 v = make_float4(0.f, 0.f, 0.f, 0.f);
            if (n < NODES) v = *(const float4*)(x + (long)n * FEAT + q);
            *(float4*)(sx + row * 132 + q) = v;
        }
        __syncthreads();

        const int n = base + ns;
        float a0 = sInb[jg], a1 = sInb[jg + 1], a2 = sInb[jg + 2], a3 = sInb[jg + 3];
        const float* xr = sx + ns * 132;
        #pragma unroll 8
        for (int k = 0; k < FEAT; k++) {
            float xv = xr[k];
            float4 w = *(const float4*)(sInW + k * STATE + jg);
            a0 += xv * w.x; a1 += xv * w.y; a2 += xv * w.z; a3 += xv * w.w;
        }
        a0 = fmaxf(a0, 0.f); a1 = fmaxf(a1, 0.f); a2 = fmaxf(a2, 0.f); a3 = fmaxf(a3, 0.f);
        if (n < NODES) *(float4*)(state + (long)n * STATE + jg) = make_float4(a0, a1, a2, a3);
        *(float4*)(ss + ns * 68 + jg) = make_float4(a0, a1, a2, a3);
        __syncthreads();

        float m0 = sMsgb[jg], m1 = sMsgb[jg + 1], m2 = sMsgb[jg + 2], m3 = sMsgb[jg + 3];
        const float* sr = ss + ns * 68;
        #pragma unroll 8
        for (int k = 0; k < STATE; k++) {
            float sv = sr[k];
            float4 w = *(const float4*)(sMsgW + k * STATE + jg);
            m0 += sv * w.x; m1 += sv * w.y; m2 += sv * w.z; m3 += sv * w.w;
        }
        m0 = fmaxf(m0, 0.f); m1 = fmaxf(m1, 0.f); m2 = fmaxf(m2, 0.f); m3 = fmaxf(m3, 0.f);
        if (n < NODES) *(float4*)(message + (long)n * STATE + jg) = make_float4(m0, m1, m2, m3);
    }
}

// ---------------------------------------------------------------------------
// CSR build
// ---------------------------------------------------------------------------
__global__ __launch_bounds__(256) void k_hist(const int* __restrict__ ei, int* __restrict__ deg)
{
    int e = blockIdx.x * 256 + threadIdx.x;
    if (e < EDGES) atomicAdd(&deg[ei[EDGES + e]], 1);
}

__global__ __launch_bounds__(1024) void k_scan(const int* __restrict__ deg,
                                               int* __restrict__ rowptr,
                                               int* __restrict__ cursor)
{
    __shared__ int wsum[16];
    __shared__ int carry;
    const int tid = threadIdx.x;
    const int lane = tid & 63, wid = tid >> 6;
    if (tid == 0) carry = 0;
    __syncthreads();
    for (int base = 0; base < NODES; base += 1024) {
        int v = (base + tid < NODES) ? deg[base + tid] : 0;
        int incl = v;
        #pragma unroll
        for (int off = 1; off < 64; off <<= 1) {
            int t = __shfl_up(incl, off, 64);
            if (lane >= off) incl += t;
        }
        if (lane == 63) wsum[wid] = incl;
        __syncthreads();
        if (tid < 16) {
            int t = wsum[tid];
            #pragma unroll
            for (int off = 1; off < 16; off <<= 1) {
                int u = __shfl_up(t, off, 64);
                if (tid >= off) t += u;
            }
            wsum[tid] = t;
        }
        __syncthreads();
        int wbase = (wid == 0) ? 0 : wsum[wid - 1];
        int excl = carry + wbase + incl - v;
        if (base + tid < NODES) { rowptr[base + tid] = excl; cursor[base + tid] = excl; }
        int tot = wsum[15];
        __syncthreads();
        if (tid == 0) carry += tot;
        __syncthreads();
    }
    if (tid == 0) rowptr[NODES] = carry;
}

__global__ __launch_bounds__(256) void k_fill(const int* __restrict__ ei,
                                              int* __restrict__ cursor,
                                              int* __restrict__ csr)
{
    int e = blockIdx.x * 256 + threadIdx.x;
    if (e < EDGES) {
        int src = ei[e];
        int dst = ei[EDGES + e];
        int slot = atomicAdd(&cursor[dst], 1);
        csr[slot] = src;
    }
}

// ---------------------------------------------------------------------------
// Pull aggregation (8-deep MLP) fused with update + next message.
// One 16-node tile per block (grid = NTILES).
// ---------------------------------------------------------------------------
__global__ __launch_bounds__(256) void k_agg_upd_msg(
    const float* __restrict__ updW, const float* __restrict__ updb,
    const float* __restrict__ msgW, const float* __restrict__ msgb,
    const int* __restrict__ rowptr, const int* __restrict__ csr,
    const float* __restrict__ msg_in,
    float* __restrict__ state, float* __restrict__ msg_out)
{
    __shared__ float sUpdW[STATE * STATE], sMsgW[STATE * STATE];
    __shared__ float sUpdb[STATE], sMsgb[STATE];
    __shared__ float sa[16 * 68], ss[16 * 68];

    for (int i = threadIdx.x; i < (STATE * STATE) / 4; i += 256) {
        *(float4*)(sUpdW + i * 4) = *(const float4*)(updW + i * 4);
        *(float4*)(sMsgW + i * 4) = *(const float4*)(msgW + i * 4);
    }
    if (threadIdx.x < STATE) {
        sUpdb[threadIdx.x] = updb[threadIdx.x];
        sMsgb[threadIdx.x] = msgb[threadIdx.x];
    }

    const int ns = threadIdx.x >> 4;
    const int jg = (threadIdx.x & 15) << 2;

    for (int base = blockIdx.x * 16; base < NODES; base += gridDim.x * 16) {
        const int n = base + ns;
        float4 acc = make_float4(0.f, 0.f, 0.f, 0.f);
        if (n < NODES) {
            int beg = rowptr[n], end = rowptr[n + 1];
            acc = gather_sum8(csr, msg_in, beg, end, jg);
        }
        __syncthreads(); // weights staged / prev-iter LDS readers done
        *(float4*)(sa + ns * 68 + jg) = acc;
        __syncthreads();

        float a0 = sUpdb[jg], a1 = sUpdb[jg + 1], a2 = sUpdb[jg + 2], a3 = sUpdb[jg + 3];
        const float* ar = sa + ns * 68;
        #pragma unroll 8
        for (int k = 0; k < STATE; k++) {
            float av = ar[k];
            float4 w = *(const float4*)(sUpdW + k * STATE + jg);
            a0 += av * w.x; a1 += av * w.y; a2 += av * w.z; a3 += av * w.w;
        }
        a0 = fmaxf(a0, 0.f); a1 = fmaxf(a1, 0.f); a2 = fmaxf(a2, 0.f); a3 = fmaxf(a3, 0.f);
        float4 st = make_float4(0.f, 0.f, 0.f, 0.f);
        if (n < NODES) st = *(const float4*)(state + (long)n * STATE + jg);
        float s0 = st.x + a0, s1 = st.y + a1, s2 = st.z + a2, s3 = st.w + a3;
        if (n < NODES) *(float4*)(state + (long)n * STATE + jg) = make_float4(s0, s1, s2, s3);
        *(float4*)(ss + ns * 68 + jg) = make_float4(s0, s1, s2, s3);
        __syncthreads();

        float m0 = sMsgb[jg], m1 = sMsgb[jg + 1], m2 = sMsgb[jg + 2], m3 = sMsgb[jg + 3];
        const float* sr = ss + ns * 68;
        #pragma unroll 8
        for (int k = 0; k < STATE; k++) {
            float sv = sr[k];
            float4 w = *(const float4*)(sMsgW + k * STATE + jg);
            m0 += sv * w.x; m1 += sv * w.y; m2 += sv * w.z; m3 += sv * w.w;
        }
        m0 = fmaxf(m0, 0.f); m1 = fmaxf(m1, 0.f); m2 = fmaxf(m2, 0.f); m3 = fmaxf(m3, 0.f);
        if (n < NODES) *(float4*)(msg_out + (long)n * STATE + jg) = make_float4(m0, m1, m2, m3);
    }
}

// ---------------------------------------------------------------------------
// Last round: aggregation + update fused with graph pooling.
// ---------------------------------------------------------------------------
__global__ __launch_bounds__(256) void k_agg_upd_pool(
    const float* __restrict__ updW, const float* __restrict__ updb,
    const int* __restrict__ rowptr, const int* __restrict__ csr,
    const float* __restrict__ msg_in,
    const float* __restrict__ state, const int* __restrict__ batch,
    float* __restrict__ gs)
{
    __shared__ float sUpdW[STATE * STATE];
    __shared__ float sUpdb[STATE];
    __shared__ float sa[16 * 68];

    for (int i = threadIdx.x; i < (STATE * STATE) / 4; i += 256)
        *(float4*)(sUpdW + i * 4) = *(const float4*)(updW + i * 4);
    if (threadIdx.x < STATE) sUpdb[threadIdx.x] = updb[threadIdx.x];

    const int ns = threadIdx.x >> 4;
    const int jg = (threadIdx.x & 15) << 2;

    for (int base = blockIdx.x * 16; base < NODES; base += gridDim.x * 16) {
        const int n = base + ns;
        float4 acc = make_float4(0.f, 0.f, 0.f, 0.f);
        if (n < NODES) {
            int beg = rowptr[n], end = rowptr[n + 1];
            acc = gather_sum8(csr, msg_in, beg, end, jg);
        }
        __syncthreads();
        *(float4*)(sa + ns * 68 + jg) = acc;
        __syncthreads();

        float a0 = sUpdb[jg], a1 = sUpdb[jg + 1], a2 = sUpdb[jg + 2], a3 = sUpdb[jg + 3];
        const float* ar = sa + ns * 68;
        #pragma unroll 8
        for (int k = 0; k < STATE; k++) {
            float av = ar[k];
            float4 w = *(const float4*)(sUpdW + k * STATE + jg);
            a0 += av * w.x; a1 += av * w.y; a2 += av * w.z; a3 += av * w.w;
        }
        a0 = fmaxf(a0, 0.f); a1 = fmaxf(a1, 0.f); a2 = fmaxf(a2, 0.f); a3 = fmaxf(a3, 0.f);
        if (n < NODES) {
            float4 st = *(const float4*)(state + (long)n * STATE + jg);
            int g = batch[n];
            float* p = gs + (long)g * STATE + jg;
            atomicAdd(p + 0, st.x + a0);
            atomicAdd(p + 1, st.y + a1);
            atomicAdd(p + 2, st.z + a2);
            atomicAdd(p + 3, st.w + a3);
        }
        __syncthreads(); // sa reuse safety for grid-stride case
    }
}

// ---------------------------------------------------------------------------
// mean = gs@meanW+b ; std = exp(0.5*clip(gs@lvW+b, -20, 2)) -> out[2,256,32]
// ---------------------------------------------------------------------------
__global__ __launch_bounds__(64) void k_final(
    const float* __restrict__ gs,
    const float* __restrict__ meanW, const float* __restrict__ meanb,
    const float* __restrict__ lvW, const float* __restrict__ lvb,
    float* __restrict__ out)
{
    __shared__ float row[STATE];
    const int g = blockIdx.x;
    const int j = threadIdx.x;
    row[j] = gs[g * STATE + j];
    __syncthreads();
    if (j < M_OUT) {
        float acc = meanb[j];
        #pragma unroll
        for (int k = 0; k < STATE; k++) acc += row[k] * meanW[k * M_OUT + j];
        out[g * M_OUT + j] = acc;
    } else {
        int jj = j - M_OUT;
        float acc = lvb[jj];
        #pragma unroll
        for (int k = 0; k < STATE; k++) acc += row[k] * lvW[k * M_OUT + jj];
        acc = fminf(fmaxf(acc, -20.f), 2.f);
        out[GRAPHS * M_OUT + g * M_OUT + jj] = expf(0.5f * acc);
    }
}

extern "C" void kernel_launch(void* const* d_in, const int* in_sizes, int n_in,
                              void* d_out, int out_size, void* d_ws, size_t ws_size,
                              hipStream_t stream) {
    const float* x     = (const float*)d_in[0];
    const int*   ei    = (const int*)d_in[1];   // [2, E]: row0 = src (gather), row1 = dst (scatter)
    const int*   batch = (const int*)d_in[2];
    const float* inW   = (const float*)d_in[3];
    const float* inb   = (const float*)d_in[4];
    const float* msgW  = (const float*)d_in[5]; // [4,64,64]
    const float* msgb  = (const float*)d_in[6]; // [4,64]
    const float* updW  = (const float*)d_in[7];
    const float* updb  = (const float*)d_in[8];
    const float* meanW = (const float*)d_in[9];
    const float* meanb = (const float*)d_in[10];
    const float* lvW   = (const float*)d_in[11];
    const float* lvb   = (const float*)d_in[12];
    float* out = (float*)d_out;

    const size_t NS = (size_t)NODES * STATE * sizeof(float); // 12.8 MB
    char* ws = (char*)d_ws;
    size_t off = 0;
    auto alloc = [&](size_t bytes) { void* p = ws + off; off += (bytes + 255) & ~(size_t)255; return p; };
    float* state   = (float*)alloc(NS);
    float* msgA    = (float*)alloc(NS);
    float* msgB    = (float*)alloc(NS);
    float* gs      = (float*)alloc((size_t)GRAPHS * STATE * sizeof(float));
    int*   deg     = (int*)alloc((size_t)NODES * sizeof(int));
    int*   rowptr  = (int*)alloc((size_t)(NODES + 1) * sizeof(int));
    int*   cursor  = (int*)alloc((size_t)NODES * sizeof(int));
    int*   csr     = (int*)alloc((size_t)EDGES * sizeof(int));

    hipMemsetAsync(deg, 0, (size_t)NODES * sizeof(int), stream);
    hipMemsetAsync(gs, 0, (size_t)GRAPHS * STATE * sizeof(float), stream);

    k_hist<<<(EDGES + 255) / 256, 256, 0, stream>>>(ei, deg);
    k_scan<<<1, 1024, 0, stream>>>(deg, rowptr, cursor);
    k_fill<<<(EDGES + 255) / 256, 256, 0, stream>>>(ei, cursor, csr);

    k_in_msg<<<NTILES, 256, 0, stream>>>(x, inW, inb, msgW, msgb, state, msgA);

    float* mi = msgA; float* mo = msgB;
    for (int r = 0; r < ROUNDS - 1; r++) {
        k_agg_upd_msg<<<NTILES, 256, 0, stream>>>(
            updW + r * STATE * STATE, updb + r * STATE,
            msgW + (r + 1) * STATE * STATE, msgb + (r + 1) * STATE,
            rowptr, csr, mi, state, mo);
        float* t = mi; mi = mo; mo = t;
    }
    k_agg_upd_pool<<<NTILES, 256, 0, stream>>>(
        updW + (ROUNDS - 1) * STATE * STATE, updb + (ROUNDS - 1) * STATE,
        rowptr, csr, mi, state, batch, gs);

    k_final<<<GRAPHS, 64, 0, stream>>>(gs, meanW, meanb, lvW, lvb, out);
}